// Round 3
// baseline (1150.657 us; speedup 1.0000x reference)
//
#include <hip/hip_runtime.h>

// ---------------------------------------------------------------------------
// DrugCell-style VNN: g = x@Wg^T + bg (4096x3008 @ 3008x16384), fused with
// term-layer-0 (tanh(g.W0+b0) + batch stats) in the GEMM epilogue; then 5
// small tanh+batchnorm term layers (TC=1, no spills), then 6->768 FC.
// R3: epilogue overlays staging LDS (total stays 32768 B -> 5 blocks/CU),
//     W0/b0 loaded into the As region post-K-loop, half-tile epilogue,
//     merged cvt kernel, wider TL1 grid.
// ---------------------------------------------------------------------------

typedef float f32x4 __attribute__((ext_vector_type(4)));
typedef __bf16 bf16x8 __attribute__((ext_vector_type(8)));

#define GL2LDS(g, l)                                                          \
  __builtin_amdgcn_global_load_lds(                                           \
      (__attribute__((address_space(1))) void*)(g),                           \
      (__attribute__((address_space(3))) void*)(l), 16, 0, 0)

__device__ __forceinline__ unsigned short f2bf(float f) {
  unsigned int u = __float_as_uint(f);
  u = u + 0x7fffu + ((u >> 16) & 1u);   // round-to-nearest-even
  return (unsigned short)(u >> 16);
}

__device__ __forceinline__ float bf2f(unsigned int lo16) {
  return __uint_as_float(lo16 << 16);
}

__device__ __forceinline__ float tanh_fast(float x) {
  float e = __expf(2.0f * x);
  return 1.0f - __fdividef(2.0f, e + 1.0f);
}

// ---------------------------------------------------------------------------
// fp32 -> bf16 conversion of x and Wg in one launch
// ---------------------------------------------------------------------------
__global__ __launch_bounds__(256) void cvt_all(
    const float* __restrict__ x, const float* __restrict__ wg,
    unsigned short* __restrict__ xb, unsigned short* __restrict__ wgb) {
  constexpr int NX = 12320768 / 4;  // x float4 count
  constexpr int NW = 49283072 / 4;  // Wg float4 count
  int i = blockIdx.x * 256 + threadIdx.x;
  const float* src;
  unsigned short* dst;
  int j;
  if (i < NX) {
    src = x; dst = xb; j = i;
  } else {
    j = i - NX;
    if (j >= NW) return;
    src = wg; dst = wgb;
  }
  float4 v = ((const float4*)src)[j];
  ushort4 o;
  o.x = f2bf(v.x); o.y = f2bf(v.y); o.z = f2bf(v.z); o.w = f2bf(v.w);
  ((ushort4*)dst)[j] = o;
}

// ---------------------------------------------------------------------------
// Fused bf16 GEMM + term-layer-0.
// C(4096 x 16384) = A(MxK) * B(NxK)^T + bg, then per block (16 terms x 128 m):
// h0[m, t*6+o] = tanh(sum_ch C[m, t*8+ch] * W0[t,o,ch] + b0[t,o]),
// batch stats (sum, sumsq) accumulated to global via atomics.
// LDS is exactly 32 KB: K-loop staging As|Bs; epilogue reuses As for W0/b0
// (floats) and Bs for a 64x128 bf16 C-half (two passes).
// ---------------------------------------------------------------------------
__global__ __launch_bounds__(256, 2) void gemm_fused(
    const unsigned short* __restrict__ A, const unsigned short* __restrict__ Bm,
    const float* __restrict__ bg, const float* __restrict__ W0,
    const float* __restrict__ b0, unsigned short* __restrict__ h0,
    float* __restrict__ stats) {
  constexpr int N = 16384, K = 3008, WOUT = 12288;
  __shared__ unsigned short smem[128 * 64 * 2];  // 32768 B exactly
  unsigned short* As = smem;
  unsigned short* Bs = smem + 128 * 64;

  const int tid = threadIdx.x;
  const int w = tid >> 6, l = tid & 63;

  // XCD-aware mapping: lin%8 ~ XCD; each XCD: 4 m-tiles x all 128 n-tiles.
  const int lin = blockIdx.x;
  const int xc = lin & 7, q = lin >> 3;
  const int mt = xc * 4 + (q & 3), nt = q >> 2;
  const int m0 = mt * 128, n0 = nt * 128;
  const int tB = nt * 16;  // first global term of this block

  const int srow = tid >> 3;                 // 0..31
  const int cs = (tid & 7) ^ (srow & 7);     // swizzled source chunk
  const unsigned short* gA = A + (size_t)(m0 + srow) * K + cs * 8;
  const unsigned short* gB = Bm + (size_t)(n0 + srow) * K + cs * 8;
  unsigned short* lA = As + w * 512;
  unsigned short* lB = Bs + w * 512;

  f32x4 acc[4][4];
#pragma unroll
  for (int i = 0; i < 4; ++i)
#pragma unroll
    for (int j = 0; j < 4; ++j) acc[i][j] = (f32x4)0.0f;

  const int quad = l >> 4;
  const int lrow = l & 15;
  const int wm = (w >> 1) * 64, wn = (w & 1) * 64;

  for (int k0 = 0; k0 < K; k0 += 64) {
#pragma unroll
    for (int j = 0; j < 4; ++j) {
      GL2LDS(gA + (size_t)j * 32 * K + k0, lA + j * 2048);
      GL2LDS(gB + (size_t)j * 32 * K + k0, lB + j * 2048);
    }
    __syncthreads();
#pragma unroll
    for (int kk = 0; kk < 2; ++kk) {
      bf16x8 av[4], bv[4];
#pragma unroll
      for (int f = 0; f < 4; ++f) {
        int ra = wm + f * 16 + lrow;
        int ca = (kk * 4 + quad) ^ (ra & 7);
        av[f] = *(const bf16x8*)(As + ra * 64 + ca * 8);
        int rb = wn + f * 16 + lrow;
        int cb = (kk * 4 + quad) ^ (rb & 7);
        bv[f] = *(const bf16x8*)(Bs + rb * 64 + cb * 8);
      }
#pragma unroll
      for (int fm = 0; fm < 4; ++fm)
#pragma unroll
        for (int fn = 0; fn < 4; ++fn)
          acc[fm][fn] = __builtin_amdgcn_mfma_f32_16x16x32_bf16(
              av[fm], bv[fn], acc[fm][fn], 0, 0, 0);
    }
    __syncthreads();
  }
  // After the final barrier all LDS reads are done -> safe to overlay.

  // ---- epilogue ----
  float* sW0 = (float*)smem;            // 768 floats (3072 B, As region)
  float* sb0 = ((float*)smem) + 768;    // 96 floats
  unsigned short* Cs = Bs;              // 64x128 bf16 C-half (16 KB)

  for (int i = tid; i < 768; i += 256) sW0[i] = W0[(size_t)tB * 48 + i];
  if (tid < 96) sb0[tid] = b0[tB * 6 + tid];

  float bgv[4];
#pragma unroll
  for (int fn = 0; fn < 4; ++fn) bgv[fn] = bg[n0 + wn + fn * 16 + lrow];

  const int t = tid >> 4;      // 0..15 local term
  const int mgrp = tid & 15;   // 16 m-groups x 4 rows per half
  const int tg = tB + t;
  float ls[6], lq[6];
#pragma unroll
  for (int o = 0; o < 6; ++o) { ls[o] = 0.0f; lq[o] = 0.0f; }

#pragma unroll
  for (int half = 0; half < 2; ++half) {
    // phase 1: the two waves owning these 64 rows store swizzled bf16 C
    if ((w >> 1) == half) {
#pragma unroll
      for (int fm = 0; fm < 4; ++fm) {
#pragma unroll
        for (int fn = 0; fn < 4; ++fn) {
          int n = wn + fn * 16 + lrow;
          int c = n >> 3, ci = n & 7;
#pragma unroll
          for (int r = 0; r < 4; ++r) {
            int mloc = fm * 16 + quad * 4 + r;  // 0..63
            int off = (((mloc >> 2) & 3) << 1) | (mloc & 1);
            Cs[mloc * 128 + (((c ^ off)) << 3) + ci] =
                f2bf(acc[fm][fn][r] + bgv[fn]);
          }
        }
      }
    }
    __syncthreads();  // C-half + (half==0) sW0/sb0 ready

    // phase 2: all 256 threads, 4 rows each: tanh-dot over 8 channels
#pragma unroll
    for (int rr = 0; rr < 4; ++rr) {
      int mloc = mgrp * 4 + rr;
      int m = half * 64 + mloc;
      int off = (((mloc >> 2) & 3) << 1) | (mloc & 1);
      uint4 u = *(const uint4*)(Cs + mloc * 128 + ((t ^ off) << 3));
      float ch[8];
      ch[0] = bf2f(u.x & 0xffffu); ch[1] = bf2f(u.x >> 16);
      ch[2] = bf2f(u.y & 0xffffu); ch[3] = bf2f(u.y >> 16);
      ch[4] = bf2f(u.z & 0xffffu); ch[5] = bf2f(u.z >> 16);
      ch[6] = bf2f(u.w & 0xffffu); ch[7] = bf2f(u.w >> 16);
      unsigned short hb[6];
#pragma unroll
      for (int o = 0; o < 6; ++o) {
        float a = sb0[t * 6 + o];
        const float* wr = &sW0[(t * 6 + o) * 8];
#pragma unroll
        for (int j = 0; j < 8; ++j) a += ch[j] * wr[j];
        float h = tanh_fast(a);
        ls[o] += h; lq[o] += h * h;
        hb[o] = f2bf(h);
      }
      unsigned int* op =
          (unsigned int*)(h0 + (size_t)(m0 + m) * WOUT + tg * 6);
      op[0] = (unsigned int)hb[0] | ((unsigned int)hb[1] << 16);
      op[1] = (unsigned int)hb[2] | ((unsigned int)hb[3] << 16);
      op[2] = (unsigned int)hb[4] | ((unsigned int)hb[5] << 16);
    }
    __syncthreads();  // protect Cs before next half overwrites
  }

  // reduce across the 16 m-groups (lanes of one width-16 shuffle group)
#pragma unroll
  for (int o = 0; o < 6; ++o) {
#pragma unroll
    for (int d = 8; d > 0; d >>= 1) {
      ls[o] += __shfl_xor(ls[o], d, 16);
      lq[o] += __shfl_xor(lq[o], d, 16);
    }
  }
  if (mgrp == 0) {
#pragma unroll
    for (int o = 0; o < 6; ++o) {
      atomicAdd(&stats[tg * 6 + o], ls[o]);
      atomicAdd(&stats[WOUT + tg * 6 + o], lq[o]);
    }
  }
}

// ---------------------------------------------------------------------------
// row loaders
// ---------------------------------------------------------------------------
template <int NCOL>
__device__ __forceinline__ void load_row(const unsigned short* p, float* d) {
  static_assert(NCOL % 8 == 0, "");
#pragma unroll
  for (int i = 0; i < NCOL / 8; ++i) {
    uint4 u = *(const uint4*)(p + i * 8);
    d[i * 8 + 0] = bf2f(u.x & 0xffffu); d[i * 8 + 1] = bf2f(u.x >> 16);
    d[i * 8 + 2] = bf2f(u.y & 0xffffu); d[i * 8 + 3] = bf2f(u.y >> 16);
    d[i * 8 + 4] = bf2f(u.z & 0xffffu); d[i * 8 + 5] = bf2f(u.z >> 16);
    d[i * 8 + 6] = bf2f(u.w & 0xffffu); d[i * 8 + 7] = bf2f(u.w >> 16);
  }
}
template <int NCOL>
__device__ __forceinline__ void load_row(const float* p, float* d) {
  static_assert(NCOL % 4 == 0, "");
#pragma unroll
  for (int i = 0; i < NCOL / 4; ++i) {
    float4 v = *(const float4*)(p + i * 4);
    d[i * 4 + 0] = v.x; d[i * 4 + 1] = v.y;
    d[i * 4 + 2] = v.z; d[i * 4 + 3] = v.w;
  }
}

// ---------------------------------------------------------------------------
// Term layer (TC=1, low VGPR): normalize prev h with prev stats, matmul
// W(T x 6 x IC), tanh, write pre-BN h, accumulate batch stats.
// Grid: (T, yChunks); block handles one term x (4096/yChunks) b's.
// ---------------------------------------------------------------------------
template <typename TIN, typename TOUT, int T, int IC>
__global__ __launch_bounds__(256) void term_layer(
    const TIN* __restrict__ in, const float* __restrict__ prevStats,
    const float* __restrict__ prevGm, const float* __restrict__ prevBt,
    const float* __restrict__ W, const float* __restrict__ bvec,
    TOUT* __restrict__ out, float* __restrict__ curStats) {
  constexpr int WIN = T * IC;
  constexpr int WOUT = T * 6;
  const int tB = blockIdx.x;

  __shared__ float sW[6 * IC];
  __shared__ float sB[6];
  __shared__ float sScale[IC];
  __shared__ float sShift[IC];
  for (int i = threadIdx.x; i < 6 * IC; i += 256)
    sW[i] = W[(size_t)tB * 6 * IC + i];
  if (threadIdx.x < 6) sB[threadIdx.x] = bvec[tB * 6 + threadIdx.x];
  if (threadIdx.x < IC) {
    int c = threadIdx.x;
    int gc = tB * IC + c;
    float mu = prevStats[gc] * (1.0f / 4096.0f);
    float var = prevStats[WIN + gc] * (1.0f / 4096.0f) - mu * mu;
    float sc = rsqrtf(var + 1e-5f) * prevGm[gc];
    sScale[c] = sc;
    sShift[c] = prevBt[gc] - mu * sc;
  }
  __syncthreads();

  float ls[6], lq[6];
#pragma unroll
  for (int i = 0; i < 6; ++i) { ls[i] = 0.0f; lq[i] = 0.0f; }

  const int bchunk = 4096 / gridDim.y;
  const int b0 = blockIdx.y * bchunk;
  for (int b = b0 + (int)threadIdx.x; b < b0 + bchunk; b += 256) {
    float child[IC];
    load_row<IC>(in + (size_t)b * WIN + (size_t)tB * IC, child);
#pragma unroll
    for (int c = 0; c < IC; ++c)
      child[c] = child[c] * sScale[c] + sShift[c];
    float hv[6];
#pragma unroll
    for (int o = 0; o < 6; ++o) {
      float a = sB[o];
      const float* wr = &sW[o * IC];
#pragma unroll
      for (int j = 0; j < IC; ++j) a += child[j] * wr[j];
      float h = tanh_fast(a);
      hv[o] = h;
      ls[o] += h;
      lq[o] += h * h;
    }
    TOUT* op = out + (size_t)b * WOUT + tB * 6;
    if constexpr (sizeof(TOUT) == 2) {
      unsigned int* oi = (unsigned int*)op;
#pragma unroll
      for (int i = 0; i < 3; ++i)
        oi[i] = (unsigned int)f2bf(hv[2 * i]) |
                ((unsigned int)f2bf(hv[2 * i + 1]) << 16);
    } else {
#pragma unroll
      for (int i = 0; i < 6; ++i) op[i] = hv[i];
    }
  }

#pragma unroll
  for (int i = 0; i < 6; ++i) {
    float s = ls[i], qq = lq[i];
#pragma unroll
    for (int d = 32; d > 0; d >>= 1) {
      s += __shfl_down(s, d, 64);
      qq += __shfl_down(qq, d, 64);
    }
    if ((threadIdx.x & 63) == 0) {
      atomicAdd(&curStats[tB * 6 + i], s);
      atomicAdd(&curStats[WOUT + tB * 6 + i], qq);
    }
  }
}

// ---------------------------------------------------------------------------
// Final: root = BN(h5) -> out(4096x768) = root @ Wf^T + bf
// ---------------------------------------------------------------------------
__global__ __launch_bounds__(256) void final_fc(
    const float* __restrict__ h5, const float* __restrict__ stats5,
    const float* __restrict__ gm5, const float* __restrict__ bt5,
    const float* __restrict__ Wf, const float* __restrict__ bfv,
    float* __restrict__ out) {
  __shared__ float sWf[768 * 6];
  __shared__ float sbf[768];
  __shared__ float sRoot[8][6];
  const int tid = threadIdx.x;
  for (int i = tid; i < 768 * 6; i += 256) sWf[i] = Wf[i];
  for (int i = tid; i < 768; i += 256) sbf[i] = bfv[i];
  const int b0 = blockIdx.x * 8;
  if (tid < 48) {
    int bb = tid / 6, o = tid % 6;
    float mu = stats5[o] * (1.0f / 4096.0f);
    float var = stats5[6 + o] * (1.0f / 4096.0f) - mu * mu;
    float sc = rsqrtf(var + 1e-5f) * gm5[o];
    sRoot[bb][o] = (h5[(size_t)(b0 + bb) * 6 + o] - mu) * sc + bt5[o];
  }
  __syncthreads();
#pragma unroll
  for (int bb = 0; bb < 8; ++bb) {
    float r0 = sRoot[bb][0], r1 = sRoot[bb][1], r2 = sRoot[bb][2];
    float r3 = sRoot[bb][3], r4 = sRoot[bb][4], r5 = sRoot[bb][5];
    for (int d = tid; d < 768; d += 256) {
      const float* wr = &sWf[d * 6];
      float a = sbf[d] + r0 * wr[0] + r1 * wr[1] + r2 * wr[2] +
                r3 * wr[3] + r4 * wr[4] + r5 * wr[5];
      out[(size_t)(b0 + bb) * 768 + d] = a;
    }
  }
}

// ---------------------------------------------------------------------------
// launch
// ---------------------------------------------------------------------------
extern "C" void kernel_launch(void* const* d_in, const int* in_sizes, int n_in,
                              void* d_out, int out_size, void* d_ws,
                              size_t ws_size, hipStream_t stream) {
  const float* x   = (const float*)d_in[0];
  const float* Wg  = (const float*)d_in[1];
  const float* bg  = (const float*)d_in[2];
  const float* W0  = (const float*)d_in[3];
  const float* b0v = (const float*)d_in[4];
  const float* gm0 = (const float*)d_in[5];
  const float* bt0 = (const float*)d_in[6];
  const float* W1  = (const float*)d_in[7];
  const float* b1v = (const float*)d_in[8];
  const float* gm1 = (const float*)d_in[9];
  const float* bt1 = (const float*)d_in[10];
  const float* W2  = (const float*)d_in[11];
  const float* b2v = (const float*)d_in[12];
  const float* gm2 = (const float*)d_in[13];
  const float* bt2 = (const float*)d_in[14];
  const float* W3  = (const float*)d_in[15];
  const float* b3v = (const float*)d_in[16];
  const float* gm3 = (const float*)d_in[17];
  const float* bt3 = (const float*)d_in[18];
  const float* W4  = (const float*)d_in[19];
  const float* b4v = (const float*)d_in[20];
  const float* gm4 = (const float*)d_in[21];
  const float* bt4 = (const float*)d_in[22];
  const float* W5  = (const float*)d_in[23];
  const float* b5v = (const float*)d_in[24];
  const float* gm5 = (const float*)d_in[25];
  const float* bt5 = (const float*)d_in[26];
  const float* Wf  = (const float*)d_in[27];
  const float* bfv = (const float*)d_in[28];

  char* ws = (char*)d_ws;
  // workspace layout (bytes), all 256-aligned
  unsigned short* Xb  = (unsigned short*)(ws + 0);            // 24,641,536
  unsigned short* Wgb = (unsigned short*)(ws + 24641536ULL);  // 98,566,144
  unsigned short* h0  = (unsigned short*)(ws + 123207680ULL); // 100,663,296 bf16
  unsigned short* h1  = (unsigned short*)(ws + 223870976ULL); // 25,165,824 bf16
  unsigned short* h2  = (unsigned short*)(ws + 249036800ULL); //  6,291,456 bf16
  float* h3 = (float*)(ws + 255328256ULL);                    //  3,145,728
  float* h4 = (float*)(ws + 258473984ULL);                    //    786,432
  float* h5 = (float*)(ws + 259260416ULL);                    //     98,304
  float* stats = (float*)(ws + 259358720ULL);                 //    131,072

  hipMemsetAsync(stats, 0, 131072, stream);

  // bf16 conversions: x (4096x3008) + Wg (16384x3008), one launch
  cvt_all<<<dim3(60160), 256, 0, stream>>>(x, Wg, Xb, Wgb);

  // fused GEMM + term-layer-0 -> h0 (bf16) + stats0
  gemm_fused<<<dim3(4096), 256, 0, stream>>>(Xb, Wgb, bg, W0, b0v, h0,
                                             stats + 0);

  // remaining term layers
  term_layer<unsigned short, unsigned short, 512, 24>
      <<<dim3(512, 8), 256, 0, stream>>>(h0, stats + 0, gm0, bt0, W1, b1v, h1,
                                         stats + 24576);
  term_layer<unsigned short, unsigned short, 128, 24>
      <<<dim3(128, 16), 256, 0, stream>>>(h1, stats + 24576, gm1, bt1, W2, b2v,
                                          h2, stats + 30720);
  term_layer<unsigned short, float, 32, 24>
      <<<dim3(32, 16), 256, 0, stream>>>(h2, stats + 30720, gm2, bt2, W3, b3v,
                                         h3, stats + 32256);
  term_layer<float, float, 8, 24>
      <<<dim3(8, 16), 256, 0, stream>>>(h3, stats + 32256, gm3, bt3, W4, b4v,
                                        h4, stats + 32640);
  term_layer<float, float, 1, 48>
      <<<dim3(1, 16), 256, 0, stream>>>(h4, stats + 32640, gm4, bt4, W5, b5v,
                                        h5, stats + 32736);

  // output FC
  final_fc<<<dim3(512), 256, 0, stream>>>(h5, stats + 32736, gm5, bt5, Wf, bfv,
                                          (float*)d_out);
}

// Round 4
// 929.842 us; speedup vs baseline: 1.2375x; 1.2375x over previous
//
#include <hip/hip_runtime.h>

// ---------------------------------------------------------------------------
// DrugCell-style VNN. R4: unfused R1 GEMM (proven 1.0 PF) + restructured
// term layers: block = TG terms x b-chunk, tid = bsub*TG + t so each wave
// reads contiguous term-slices of a row (coalesced), per-thread state is
// child[IC]+ls/lq[6] (no spills). Stats: LDS reduce -> 1 atomic/(t,o,block).
// ---------------------------------------------------------------------------

typedef float f32x4 __attribute__((ext_vector_type(4)));
typedef __bf16 bf16x8 __attribute__((ext_vector_type(8)));

#define GL2LDS(g, l)                                                          \
  __builtin_amdgcn_global_load_lds(                                           \
      (__attribute__((address_space(1))) void*)(g),                           \
      (__attribute__((address_space(3))) void*)(l), 16, 0, 0)

__device__ __forceinline__ unsigned short f2bf(float f) {
  unsigned int u = __float_as_uint(f);
  u = u + 0x7fffu + ((u >> 16) & 1u);   // round-to-nearest-even
  return (unsigned short)(u >> 16);
}

__device__ __forceinline__ float bf2f(unsigned int lo16) {
  return __uint_as_float(lo16 << 16);
}

__device__ __forceinline__ float tanh_fast(float x) {
  float e = __expf(2.0f * x);
  return 1.0f - __fdividef(2.0f, e + 1.0f);
}

// ---------------------------------------------------------------------------
// fp32 -> bf16 conversion of x and Wg in one launch
// ---------------------------------------------------------------------------
__global__ __launch_bounds__(256) void cvt_all(
    const float* __restrict__ x, const float* __restrict__ wg,
    unsigned short* __restrict__ xb, unsigned short* __restrict__ wgb) {
  constexpr int NX = 12320768 / 4;
  constexpr int NW = 49283072 / 4;
  int i = blockIdx.x * 256 + threadIdx.x;
  const float* src;
  unsigned short* dst;
  int j;
  if (i < NX) {
    src = x; dst = xb; j = i;
  } else {
    j = i - NX;
    if (j >= NW) return;
    src = wg; dst = wgb;
  }
  float4 v = ((const float4*)src)[j];
  ushort4 o;
  o.x = f2bf(v.x); o.y = f2bf(v.y); o.z = f2bf(v.z); o.w = f2bf(v.w);
  ((ushort4*)dst)[j] = o;
}

// ---------------------------------------------------------------------------
// bf16 GEMM (R1 exact): C(4096x16384) = A(MxK)*B(NxK)^T + bias[n], K=3008.
// ---------------------------------------------------------------------------
__global__ __launch_bounds__(256, 2) void gemm_bt(
    const unsigned short* __restrict__ A, const unsigned short* __restrict__ Bm,
    const float* __restrict__ bias, unsigned short* __restrict__ C) {
  constexpr int N = 16384, K = 3008;
  __shared__ unsigned short As[128 * 64];
  __shared__ unsigned short Bs[128 * 64];
  const int tid = threadIdx.x;
  const int w = tid >> 6, l = tid & 63;
  const int m0 = blockIdx.y * 128, n0 = blockIdx.x * 128;

  const int srow = tid >> 3;
  const int cs = (tid & 7) ^ (srow & 7);
  const unsigned short* gA = A + (size_t)(m0 + srow) * K + cs * 8;
  const unsigned short* gB = Bm + (size_t)(n0 + srow) * K + cs * 8;
  unsigned short* lA = As + w * 512;
  unsigned short* lB = Bs + w * 512;

  f32x4 acc[4][4];
#pragma unroll
  for (int i = 0; i < 4; ++i)
#pragma unroll
    for (int j = 0; j < 4; ++j) acc[i][j] = (f32x4)0.0f;

  const int quad = l >> 4;
  const int lrow = l & 15;
  const int wm = (w >> 1) * 64, wn = (w & 1) * 64;

  for (int k0 = 0; k0 < K; k0 += 64) {
#pragma unroll
    for (int j = 0; j < 4; ++j) {
      GL2LDS(gA + (size_t)j * 32 * K + k0, lA + j * 2048);
      GL2LDS(gB + (size_t)j * 32 * K + k0, lB + j * 2048);
    }
    __syncthreads();
#pragma unroll
    for (int kk = 0; kk < 2; ++kk) {
      bf16x8 av[4], bv[4];
#pragma unroll
      for (int f = 0; f < 4; ++f) {
        int ra = wm + f * 16 + lrow;
        int ca = (kk * 4 + quad) ^ (ra & 7);
        av[f] = *(const bf16x8*)(As + ra * 64 + ca * 8);
        int rb = wn + f * 16 + lrow;
        int cb = (kk * 4 + quad) ^ (rb & 7);
        bv[f] = *(const bf16x8*)(Bs + rb * 64 + cb * 8);
      }
#pragma unroll
      for (int fm = 0; fm < 4; ++fm)
#pragma unroll
        for (int fn = 0; fn < 4; ++fn)
          acc[fm][fn] = __builtin_amdgcn_mfma_f32_16x16x32_bf16(
              av[fm], bv[fn], acc[fm][fn], 0, 0, 0);
    }
    __syncthreads();
  }

  // epilogue: C/D layout col=lane&15, row=quad*4+reg
#pragma unroll
  for (int fn = 0; fn < 4; ++fn) {
    int n = n0 + wn + fn * 16 + lrow;
    float bn = bias[n];
#pragma unroll
    for (int fm = 0; fm < 4; ++fm) {
      int mbase = m0 + wm + fm * 16 + quad * 4;
#pragma unroll
      for (int r = 0; r < 4; ++r) {
        float v = acc[fm][fn][r] + bn;
        C[(size_t)(mbase + r) * N + n] = f2bf(v);
      }
    }
  }
}

// ---------------------------------------------------------------------------
// row loaders (term-slice of IC elements)
// ---------------------------------------------------------------------------
template <int IC>
__device__ __forceinline__ void load_row(const unsigned short* p, float* d) {
  static_assert(IC % 8 == 0, "");
#pragma unroll
  for (int i = 0; i < IC / 8; ++i) {
    uint4 u = *(const uint4*)(p + i * 8);
    d[i * 8 + 0] = bf2f(u.x & 0xffffu); d[i * 8 + 1] = bf2f(u.x >> 16);
    d[i * 8 + 2] = bf2f(u.y & 0xffffu); d[i * 8 + 3] = bf2f(u.y >> 16);
    d[i * 8 + 4] = bf2f(u.z & 0xffffu); d[i * 8 + 5] = bf2f(u.z >> 16);
    d[i * 8 + 6] = bf2f(u.w & 0xffffu); d[i * 8 + 7] = bf2f(u.w >> 16);
  }
}
template <int IC>
__device__ __forceinline__ void load_row(const float* p, float* d) {
  static_assert(IC % 4 == 0, "");
#pragma unroll
  for (int i = 0; i < IC / 4; ++i) {
    float4 v = *(const float4*)(p + i * 4);
    d[i * 4 + 0] = v.x; d[i * 4 + 1] = v.y;
    d[i * 4 + 2] = v.z; d[i * 4 + 3] = v.w;
  }
}

// ---------------------------------------------------------------------------
// Term layer: block = TG terms x (4096/gridDim.y) b's; tid = bsub*TG + t.
// Wave lanes cover consecutive terms -> contiguous row-slice reads.
// ---------------------------------------------------------------------------
template <typename TIN, typename TOUT, int T, int IC, int TG, bool FIRST>
__global__ __launch_bounds__(256) void term_layer(
    const TIN* __restrict__ in, const float* __restrict__ prevStats,
    const float* __restrict__ prevGm, const float* __restrict__ prevBt,
    const float* __restrict__ W, const float* __restrict__ bvec,
    TOUT* __restrict__ out, float* __restrict__ curStats) {
  constexpr int WIN = T * IC;
  constexpr int WOUT = T * 6;
  constexpr int NB = 256 / TG;
  const int tb = blockIdx.x * TG;
  const int t = threadIdx.x & (TG - 1);
  const int bsub = threadIdx.x / TG;

  __shared__ float sW[TG * 6 * IC];
  __shared__ float sB[TG * 6];
  __shared__ float sScale[FIRST ? 1 : TG * IC];
  __shared__ float sShift[FIRST ? 1 : TG * IC];
  __shared__ float sRed[256][13];  // 13: odd stride, conflict-free

  for (int i = threadIdx.x; i < TG * 6 * IC; i += 256)
    sW[i] = W[(size_t)tb * 6 * IC + i];
  for (int i = threadIdx.x; i < TG * 6; i += 256) sB[i] = bvec[tb * 6 + i];
  if constexpr (!FIRST) {
    for (int i = threadIdx.x; i < TG * IC; i += 256) {
      int gc = tb * IC + i;
      float mu = prevStats[gc] * (1.0f / 4096.0f);
      float var = prevStats[WIN + gc] * (1.0f / 4096.0f) - mu * mu;
      float sc = rsqrtf(var + 1e-5f) * prevGm[gc];
      sScale[i] = sc;
      sShift[i] = prevBt[gc] - mu * sc;
    }
  }
  __syncthreads();

  float ls[6], lq[6];
#pragma unroll
  for (int i = 0; i < 6; ++i) { ls[i] = 0.0f; lq[i] = 0.0f; }

  const int bchunk = 4096 / gridDim.y;
  const int rows = bchunk / NB;
  const int b0 = blockIdx.y * bchunk + bsub * rows;
  for (int i = 0; i < rows; ++i) {
    int b = b0 + i;
    float child[IC];
    load_row<IC>(in + (size_t)b * WIN + (size_t)(tb + t) * IC, child);
    if constexpr (!FIRST) {
#pragma unroll
      for (int c = 0; c < IC; ++c)
        child[c] = child[c] * sScale[t * IC + c] + sShift[t * IC + c];
    }
    float hv[6];
#pragma unroll
    for (int o = 0; o < 6; ++o) {
      float a = sB[t * 6 + o];
      const float* wr = &sW[(t * 6 + o) * IC];
#pragma unroll
      for (int j = 0; j < IC; ++j) a += child[j] * wr[j];
      float h = tanh_fast(a);
      hv[o] = h;
      ls[o] += h;
      lq[o] += h * h;
    }
    TOUT* op = out + (size_t)b * WOUT + (size_t)(tb + t) * 6;
    if constexpr (sizeof(TOUT) == 2) {
      unsigned int* oi = (unsigned int*)op;
#pragma unroll
      for (int i2 = 0; i2 < 3; ++i2)
        oi[i2] = (unsigned int)f2bf(hv[2 * i2]) |
                 ((unsigned int)f2bf(hv[2 * i2 + 1]) << 16);
    } else {
#pragma unroll
      for (int i2 = 0; i2 < 6; ++i2) op[i2] = hv[i2];
    }
  }

  // stats: stage per-thread partials, reduce over NB bsubs, 1 atomic each
#pragma unroll
  for (int j = 0; j < 6; ++j) {
    sRed[threadIdx.x][j] = ls[j];
    sRed[threadIdx.x][6 + j] = lq[j];
  }
  __syncthreads();
  for (int i = threadIdx.x; i < TG * 6; i += 256) {
    int tt = i / 6, o = i % 6;
    float s = 0.0f, q = 0.0f;
    for (int nb = 0; nb < NB; ++nb) {
      s += sRed[nb * TG + tt][o];
      q += sRed[nb * TG + tt][6 + o];
    }
    atomicAdd(&curStats[(tb + tt) * 6 + o], s);
    atomicAdd(&curStats[WOUT + (tb + tt) * 6 + o], q);
  }
}

// ---------------------------------------------------------------------------
// Final: root = BN(h5) -> out(4096x768) = root @ Wf^T + bf
// ---------------------------------------------------------------------------
__global__ __launch_bounds__(256) void final_fc(
    const float* __restrict__ h5, const float* __restrict__ stats5,
    const float* __restrict__ gm5, const float* __restrict__ bt5,
    const float* __restrict__ Wf, const float* __restrict__ bfv,
    float* __restrict__ out) {
  __shared__ float sWf[768 * 6];
  __shared__ float sbf[768];
  __shared__ float sRoot[8][6];
  const int tid = threadIdx.x;
  for (int i = tid; i < 768 * 6; i += 256) sWf[i] = Wf[i];
  for (int i = tid; i < 768; i += 256) sbf[i] = bfv[i];
  const int b0 = blockIdx.x * 8;
  if (tid < 48) {
    int bb = tid / 6, o = tid % 6;
    float mu = stats5[o] * (1.0f / 4096.0f);
    float var = stats5[6 + o] * (1.0f / 4096.0f) - mu * mu;
    float sc = rsqrtf(var + 1e-5f) * gm5[o];
    sRoot[bb][o] = (h5[(size_t)(b0 + bb) * 6 + o] - mu) * sc + bt5[o];
  }
  __syncthreads();
#pragma unroll
  for (int bb = 0; bb < 8; ++bb) {
    float r0 = sRoot[bb][0], r1 = sRoot[bb][1], r2 = sRoot[bb][2];
    float r3 = sRoot[bb][3], r4 = sRoot[bb][4], r5 = sRoot[bb][5];
    for (int d = tid; d < 768; d += 256) {
      const float* wr = &sWf[d * 6];
      float a = sbf[d] + r0 * wr[0] + r1 * wr[1] + r2 * wr[2] +
                r3 * wr[3] + r4 * wr[4] + r5 * wr[5];
      out[(size_t)(b0 + bb) * 768 + d] = a;
    }
  }
}

// ---------------------------------------------------------------------------
// launch
// ---------------------------------------------------------------------------
extern "C" void kernel_launch(void* const* d_in, const int* in_sizes, int n_in,
                              void* d_out, int out_size, void* d_ws,
                              size_t ws_size, hipStream_t stream) {
  const float* x   = (const float*)d_in[0];
  const float* Wg  = (const float*)d_in[1];
  const float* bg  = (const float*)d_in[2];
  const float* W0  = (const float*)d_in[3];
  const float* b0v = (const float*)d_in[4];
  const float* gm0 = (const float*)d_in[5];
  const float* bt0 = (const float*)d_in[6];
  const float* W1  = (const float*)d_in[7];
  const float* b1v = (const float*)d_in[8];
  const float* gm1 = (const float*)d_in[9];
  const float* bt1 = (const float*)d_in[10];
  const float* W2  = (const float*)d_in[11];
  const float* b2v = (const float*)d_in[12];
  const float* gm2 = (const float*)d_in[13];
  const float* bt2 = (const float*)d_in[14];
  const float* W3  = (const float*)d_in[15];
  const float* b3v = (const float*)d_in[16];
  const float* gm3 = (const float*)d_in[17];
  const float* bt3 = (const float*)d_in[18];
  const float* W4  = (const float*)d_in[19];
  const float* b4v = (const float*)d_in[20];
  const float* gm4 = (const float*)d_in[21];
  const float* bt4 = (const float*)d_in[22];
  const float* W5  = (const float*)d_in[23];
  const float* b5v = (const float*)d_in[24];
  const float* gm5 = (const float*)d_in[25];
  const float* bt5 = (const float*)d_in[26];
  const float* Wf  = (const float*)d_in[27];
  const float* bfv = (const float*)d_in[28];

  char* ws = (char*)d_ws;
  unsigned short* Xb  = (unsigned short*)(ws + 0);            // 24,641,536
  unsigned short* Wgb = (unsigned short*)(ws + 24641536ULL);  // 98,566,144
  unsigned short* G   = (unsigned short*)(ws + 123207680ULL); // 134,217,728
  unsigned short* h0  = (unsigned short*)(ws + 257425408ULL); // 100,663,296
  unsigned short* h1  = (unsigned short*)(ws + 358088704ULL); // 25,165,824
  unsigned short* h2  = (unsigned short*)(ws + 383254528ULL); //  6,291,456
  float* h3 = (float*)(ws + 389545984ULL);                    //  3,145,728
  float* h4 = (float*)(ws + 392691712ULL);                    //    786,432
  float* h5 = (float*)(ws + 393478144ULL);                    //     98,304
  float* stats = (float*)(ws + 393576448ULL);                 //    131,072

  hipMemsetAsync(stats, 0, 131072, stream);

  cvt_all<<<dim3(60160), 256, 0, stream>>>(x, Wg, Xb, Wgb);

  gemm_bt<<<dim3(128, 32), 256, 0, stream>>>(Xb, Wgb, bg, G);

  term_layer<unsigned short, unsigned short, 2048, 8, 64, true>
      <<<dim3(32, 16), 256, 0, stream>>>(G, nullptr, nullptr, nullptr, W0, b0v,
                                         h0, stats + 0);
  term_layer<unsigned short, unsigned short, 512, 24, 32, false>
      <<<dim3(16, 32), 256, 0, stream>>>(h0, stats + 0, gm0, bt0, W1, b1v, h1,
                                         stats + 24576);
  term_layer<unsigned short, unsigned short, 128, 24, 32, false>
      <<<dim3(4, 64), 256, 0, stream>>>(h1, stats + 24576, gm1, bt1, W2, b2v,
                                        h2, stats + 30720);
  term_layer<unsigned short, float, 32, 24, 32, false>
      <<<dim3(1, 128), 256, 0, stream>>>(h2, stats + 30720, gm2, bt2, W3, b3v,
                                         h3, stats + 32256);
  term_layer<float, float, 8, 24, 8, false>
      <<<dim3(1, 64), 256, 0, stream>>>(h3, stats + 32256, gm3, bt3, W4, b4v,
                                        h4, stats + 32640);
  term_layer<float, float, 1, 48, 1, false>
      <<<dim3(1, 16), 256, 0, stream>>>(h4, stats + 32640, gm4, bt4, W5, b5v,
                                        h5, stats + 32736);

  final_fc<<<dim3(512), 256, 0, stream>>>(h5, stats + 32736, gm5, bt5, Wf, bfv,
                                          (float*)d_out);
}